// Round 1
// baseline (1710.694 us; speedup 1.0000x reference)
//
#include <hip/hip_runtime.h>
#include <hip/hip_fp16.h>
#include <stdint.h>

typedef _Float16 f16;
typedef _Float16 f16x8 __attribute__((ext_vector_type(8)));
typedef float f32x4 __attribute__((ext_vector_type(4)));

#define NROWS 262144
#define MROWS 16            // rows per group
#define TPB   512           // 8 waves
#define GPB   8             // row-groups per block (table reused across these)
#define NBLK  (NROWS / (MROWS * GPB))   // 2048
#define K     192           // padded vocab
#define THR   0.9921875f

// workspace byte offsets (all f16)
#define WS_TABT 0                        // [768][192]
#define WS_W2FS (768 * 192 * 2)          // [16][768]
#define WS_W2VA (WS_W2FS + 16 * 768 * 2) // [16][640]

// LDS layout (time-multiplexed):
//  phase A: cntfx  int  [4][16][192]         @0      (49152)
//  phase B: cnt16  f16  [4][16][200]         @0      (25600)
//  phase C: fsfeat f16  [16][776]            @0      (24832)
//           vafeat f16  [16][648]            @24832  (20736, ends 45568)
//  always : facc/vacc f32 [256]+[256]        @49152  (2048)  -- outside count grid
// total 51200 B -> 3 blocks/CU (3*51200 = 153600 <= 163840)
#define FS_STRIDE 776
#define VA_STRIDE 648
#define VA_BASE   24832
#define ACC_BASE  49152
#define SMEM_SZ   51200

__device__ __forceinline__ f16x8 bc8(uint4 u) {
  union { uint4 u; f16x8 h; } x; x.u = u; return x.h;
}
__device__ __forceinline__ float clampv(float x) {
  return fminf(fmaxf(x, -THR), THR);
}
__device__ __forceinline__ uint32_t packh2(float a, float b) {
  union { __half2 h; uint32_t u; } cv; cv.h = __floats2half2_rn(a, b); return cv.u;
}

// ---------------- prepack ----------------------------------------------------
// blocks 0..23: table transpose via LDS tile (coalesced both sides)
// blocks 24.. : layer-2 weight pack (already coalesced)
__global__ void prepack(const float* __restrict__ emb_fs, const float* __restrict__ emb_va,
                        const float* __restrict__ emb_ha, const float* __restrict__ emb_ra,
                        const float* __restrict__ fs_w,   const float* __restrict__ absva_w,
                        const float* __restrict__ absha_w,const float* __restrict__ absra_w,
                        const float* __restrict__ va_w,   const float* __restrict__ fsxva_w,
                        const float* __restrict__ haxra_w, f16* __restrict__ ws) {
  if (blockIdx.x < 24) {
    __shared__ float tile[192 * 33];
    int u0 = blockIdx.x * 32;
    int t = threadIdx.x;
    #pragma unroll 4
    for (int i = 0; i < 24; ++i) {
      int idx = t + 256 * i;            // 6144 = 192k x 32u
      int k = idx >> 5;
      int c = idx & 31;
      int u = u0 + c;
      float v = 0.f;
      if (k < 185) {
        if      (u < 256) v = emb_fs[k * 256 + u];
        else if (u < 512) v = emb_va[k * 256 + (u - 256)];
        else if (u < 640) v = emb_ha[k * 128 + (u - 512)];
        else              v = emb_ra[k * 128 + (u - 640)];
      }
      tile[k * 33 + c] = v;
    }
    __syncthreads();
    #pragma unroll 4
    for (int i = 0; i < 24; ++i) {
      int idx = t + 256 * i;
      int u = idx / 192;
      int k = idx % 192;
      ws[(u0 + u) * 192 + k] = (f16)tile[k * 33 + u];
    }
  } else {
    int gid = (blockIdx.x - 24) * 256 + threadIdx.x;
    if (gid < 16 * 768) {                        // w2fs[j][k]
      int j = gid / 768, k = gid % 768;
      float v = (k < 256) ? fs_w[j * 256 + k]
              : (k < 512) ? absva_w[j * 256 + (k - 256)]
              : (k < 640) ? absha_w[j * 128 + (k - 512)]
                          : absra_w[j * 128 + (k - 640)];
      ((f16*)((char*)ws + WS_W2FS))[j * 768 + k] = (f16)v;
    } else if (gid < 16 * 768 + 16 * 640) {      // w2va[j][k]
      int g = gid - 16 * 768;
      int j = g / 640, k = g % 640;
      float v = (k < 256) ? va_w[j * 256 + k]
              : (k < 512) ? fsxva_w[j * 256 + (k - 256)]
                          : haxra_w[j * 128 + (k - 512)];
      ((f16*)((char*)ws + WS_W2VA))[j * 640 + k] = (f16)v;
    }
  }
}

// ---------------- main fused kernel ------------------------------------------
__global__ __launch_bounds__(TPB, 6)   // 6 waves/EU -> 3 blocks/CU
void rengar_main(const int* __restrict__ pst_idx, const float* __restrict__ color_sign,
                 const float* __restrict__ sob_sign, const float* __restrict__ wtm,
                 const float* __restrict__ tempo_w, const float* __restrict__ fs_b,
                 const float* __restrict__ out_va_w, const float* __restrict__ out_fsxva_w,
                 const f16* __restrict__ ws, float* __restrict__ out) {
  __shared__ __align__(16) char smem[SMEM_SZ];

  const int tid  = threadIdx.x;
  const int lane = tid & 63;
  const int w    = tid >> 6;          // wave 0..7
  const int l15  = lane & 15;
  const int q    = lane >> 4;

  const f16* tabT = (const f16*)((const char*)ws + WS_TABT);
  float* facc = (float*)(smem + ACC_BASE);
  float* vacc = facc + 256;

  // ---- hoist layer-1 A fragments: 6 tiles/wave, reused across all groups ----
  uint4 afr1[36];
  int   tbs[6];
  #pragma unroll
  for (int i = 0; i < 6; ++i) {
    int t  = w * 6 + i;
    int u0 = t * 16;
    tbs[i] = (u0 < 256) ? 0 : (u0 < 512) ? 1 : (u0 < 640) ? 2 : 3;
    const f16* ap = tabT + (u0 + l15) * K + q * 8;
    #pragma unroll
    for (int ks = 0; ks < 6; ++ks) afr1[i * 6 + ks] = *(const uint4*)(ap + ks * 32);
  }

  // ---- hoist layer-2 A fragments (split-K: fs -> waves 0-3, va -> waves 4-7)
  uint4 a2[6];
  if (w < 4) {
    const f16* A = (const f16*)((const char*)ws + WS_W2FS) + l15 * 768 + w * 192 + q * 8;
    #pragma unroll
    for (int ks = 0; ks < 6; ++ks) a2[ks] = *(const uint4*)(A + ks * 32);
  } else {
    const f16* A = (const f16*)((const char*)ws + WS_W2VA) + l15 * 640 + (w - 4) * 160 + q * 8;
    #pragma unroll
    for (int ks = 0; ks < 5; ++ks) a2[ks] = *(const uint4*)(A + ks * 32);
  }

  float bj = 0.f, w1j = 0.f, w2j = 0.f;
  if (tid < 256) {
    int j = tid & 15;                  // output index (accum word = batch*16 + swz(j))
    bj  = fs_b[j];
    w1j = out_va_w[j];
    w2j = out_fsxva_w[j];
  }

  // ---- prefetch group-0 inputs ----
  const int ebase = blockIdx.x * GPB * 512;
  int   vidx = pst_idx[ebase + tid];
  float cc   = color_sign[ebase + tid];
  float ss   = sob_sign[ebase + tid];
  float wtr  = wtm[blockIdx.x * GPB * MROWS + l15];

  // ---- prologue: zero count grid + accumulators (3200 int4 = 51200 B) ----
  {
    int4 z = make_int4(0, 0, 0, 0);
    int4* p = (int4*)smem;
    #pragma unroll
    for (int i = 0; i < 7; ++i) {
      int idx = tid + 512 * i;
      if (idx < 3200) p[idx] = z;
    }
  }
  __syncthreads();

  #pragma unroll 1
  for (int g = 0; g < GPB; ++g) {
    const int r0 = (blockIdx.x * GPB + g) * MROWS;

    // ---- P2: scatter (LDS int atomics, scale 2^16) -- grid pre-zeroed
    {
      int* cntfx = (int*)smem;
      int  row = tid >> 5;
      int* base = cntfx + row * K + vidx;
      atomicAdd(base + 0 * MROWS * K, 65536);
      atomicAdd(base + 1 * MROWS * K, __float2int_rn(cc * 65536.f));
      atomicAdd(base + 2 * MROWS * K, __float2int_rn(ss * 65536.f));
      atomicAdd(base + 3 * MROWS * K, __float2int_rn(cc * ss * 65536.f));
    }
    // prefetch next group's inputs (latency hidden behind this group's work)
    float nwt = wtr;
    if (g + 1 < GPB) {
      int nb = ebase + (g + 1) * 512;
      vidx = pst_idx[nb + tid];
      cc   = color_sign[nb + tid];
      ss   = sob_sign[nb + tid];
      nwt  = wtm[r0 + MROWS + l15];
    }
    __syncthreads();                                       // (1)

    // ---- P3a: conflict-free lane-consecutive b128 reads of the int grid
    int4 v4[6];
    {
      const int4* src = (const int4*)smem;
      #pragma unroll
      for (int i = 0; i < 6; ++i) v4[i] = src[tid + 512 * i];
    }
    __syncthreads();                                       // (2)

    // ---- P3b: int -> f16 counts, re-layout [tb][row][stride 100 u32]
    //      lane-consecutive uint2 (b64) writes: conflict-free
    {
      const float inv = 1.f / 65536.f;
      #pragma unroll
      for (int i = 0; i < 6; ++i) {
        int idx = tid + 512 * i;            // int4 index; covers 4 ints of one row
        int tb  = idx / 768;
        int rem = idx - tb * 768;
        int row = rem / 48;
        int k2  = (rem - row * 48) * 2;     // (k0>>1), even
        uint32_t* dst = (uint32_t*)smem + tb * 1600 + row * 100 + k2;
        uint2 o;
        o.x = packh2(v4[i].x * inv, v4[i].y * inv);
        o.y = packh2(v4[i].z * inv, v4[i].w * inv);
        *(uint2*)dst = o;
      }
    }
    __syncthreads();                                       // (3)

    // ---- P4: layer-1 GEMM (A register-resident, B from LDS counts)
    f32x4 acc[6];
    {
      uint4 bfr[6];
      int tb_cur = -1;
      #pragma unroll
      for (int i = 0; i < 6; ++i) {
        int tb = tbs[i];
        if (tb != tb_cur) {
          tb_cur = tb;
          #pragma unroll
          for (int ks = 0; ks < 6; ++ks) {
            const uint32_t* p = (const uint32_t*)smem + tb * 1600 + l15 * 100 + ks * 16 + q * 4;
            bfr[ks] = *(const uint4*)p;
          }
        }
        f32x4 a = {0.f, 0.f, 0.f, 0.f};
        #pragma unroll
        for (int ks = 0; ks < 6; ++ks)
          a = __builtin_amdgcn_mfma_f32_16x16x32_f16(bc8(afr1[i * 6 + ks]), bc8(bfr[ks]), a, 0, 0, 0);
        acc[i] = a;
      }
    }
    __syncthreads();   // (4) counts dead; LDS becomes feature space

    // ---- P5: primary features (D: col=l15=batch row, m=q*4+reg=u)
    {
      #pragma unroll
      for (int i = 0; i < 6; ++i) {
        int t  = w * 6 + i;
        int u0 = t * 16;
        int tb = tbs[i];
        int m0 = u0 + q * 4;
        f32x4 a = acc[i];
        if (tb == 0) {
          __half2* d = (__half2*)(smem + l15 * (FS_STRIDE * 2) + m0 * 2);
          d[0] = __floats2half2_rn(clampv(a[0]), clampv(a[1]));
          d[1] = __floats2half2_rn(clampv(a[2]), clampv(a[3]));
        } else if (tb == 1) {
          int s0 = m0 - 256;
          float4 tw = *(const float4*)(tempo_w + s0);
          float b0 = clampv(a[0] + wtr * tw.x);
          float b1 = clampv(a[1] + wtr * tw.y);
          float b2 = clampv(a[2] + wtr * tw.z);
          float b3 = clampv(a[3] + wtr * tw.w);
          __half2* dv = (__half2*)(smem + VA_BASE + l15 * (VA_STRIDE * 2) + s0 * 2);
          dv[0] = __floats2half2_rn(b0, b1);
          dv[1] = __floats2half2_rn(b2, b3);
          __half2* df = (__half2*)(smem + l15 * (FS_STRIDE * 2) + (256 + s0) * 2);
          df[0] = __floats2half2_rn(fabsf(b0), fabsf(b1));
          df[1] = __floats2half2_rn(fabsf(b2), fabsf(b3));
        } else if (tb == 2) {
          int s0 = m0 - 512;
          __half2* d = (__half2*)(smem + l15 * (FS_STRIDE * 2) + (512 + s0) * 2);
          d[0] = __floats2half2_rn(clampv(a[0]), clampv(a[1]));
          d[1] = __floats2half2_rn(clampv(a[2]), clampv(a[3]));
        } else {
          int s0 = m0 - 640;
          __half2* d = (__half2*)(smem + l15 * (FS_STRIDE * 2) + (640 + s0) * 2);
          d[0] = __floats2half2_rn(clampv(a[0]), clampv(a[1]));
          d[1] = __floats2half2_rn(clampv(a[2]), clampv(a[3]));
        }
      }
    }
    __syncthreads();                                       // (5)

    // ---- P6: derived features: ab, |h|, |r|, h*r
    {
      uint32_t* fs32 = (uint32_t*)smem;
      uint32_t* va32 = (uint32_t*)(smem + VA_BASE);
      #pragma unroll
      for (int it = 0; it < 6; ++it) {
        int p = tid + 512 * it;
        if (p < 2048) {
          int row = p >> 7, kp = p & 127;
          union { uint32_t u; __half2 h; } a, b, r;
          a.u = fs32[row * 388 + kp];
          b.u = va32[row * 324 + kp];
          r.h = __hmul2(a.h, b.h);
          va32[row * 324 + 128 + kp] = r.u;
        } else {
          int pc = p - 2048;
          int row = pc >> 6, kp = pc & 63;
          union { uint32_t u; __half2 h; } h2, r2, pr;
          h2.u = fs32[row * 388 + 256 + kp];
          r2.u = fs32[row * 388 + 320 + kp];
          pr.h = __hmul2(h2.h, r2.h);
          fs32[row * 388 + 256 + kp] = h2.u & 0x7FFF7FFFu;
          fs32[row * 388 + 320 + kp] = r2.u & 0x7FFF7FFFu;
          va32[row * 324 + 256 + kp] = pr.u;
        }
      }
    }
    __syncthreads();                                       // (6)

    // ---- P7: layer-2 split-K across all 8 waves, combine via LDS f32 atomics
    {
      f32x4 a2acc = {0.f, 0.f, 0.f, 0.f};
      if (w < 4) {
        #pragma unroll
        for (int ks = 0; ks < 6; ++ks) {
          int k = w * 192 + ks * 32 + q * 8;
          uint4 bf = *(const uint4*)(smem + l15 * (FS_STRIDE * 2) + k * 2);
          a2acc = __builtin_amdgcn_mfma_f32_16x16x32_f16(bc8(a2[ks]), bc8(bf), a2acc, 0, 0, 0);
        }
      } else {
        #pragma unroll
        for (int ks = 0; ks < 5; ++ks) {
          int k = (w - 4) * 160 + ks * 32 + q * 8;
          uint4 bf = *(const uint4*)(smem + VA_BASE + l15 * (VA_STRIDE * 2) + k * 2);
          a2acc = __builtin_amdgcn_mfma_f32_16x16x32_f16(bc8(a2[ks]), bc8(bf), a2acc, 0, 0, 0);
        }
      }
      float* dstacc = (w < 4) ? facc : vacc;
      int base = l15 << 4;               // l15 = batch row (D col)
      #pragma unroll
      for (int r = 0; r < 4; ++r) {
        int j = q * 4 + r;               // output index
        atomicAdd(&dstacc[base + ((j + l15) & 15)], a2acc[r]);  // XOR-stagger: 2-way banks
      }
    }
    __syncthreads();                                       // (7)

    // ---- P8: waves 0-3: read accum (+re-zero), bias/clamp, 16-lane shfl reduce, out.
    //          waves 4-7: re-zero the 48 KiB count grid for the next group.
    if (tid < 256) {
      int b = tid >> 4, j = tid & 15;
      int idx = (b << 4) | ((j + b) & 15);
      float f = facc[idx];
      float v = vacc[idx];
      facc[idx] = 0.f;
      vacc[idx] = 0.f;
      f = clampv(f + bj);
      v = clampv(v);
      float rr = v * w1j + f * v * w2j;
      rr += __shfl_xor(rr, 1);
      rr += __shfl_xor(rr, 2);
      rr += __shfl_xor(rr, 4);
      rr += __shfl_xor(rr, 8);
      if (j == 0) out[r0 + b] = rr;
    } else if (g + 1 < GPB) {
      int4 z = make_int4(0, 0, 0, 0);
      int4* p = (int4*)smem;
      int t2 = tid - 256;
      #pragma unroll
      for (int i = 0; i < 12; ++i) p[t2 + 256 * i] = z;    // words 0..12287
    }
    __syncthreads();                                       // (8)
    wtr = nwt;
  }
}

extern "C" void kernel_launch(void* const* d_in, const int* in_sizes, int n_in,
                              void* d_out, int out_size, void* d_ws, size_t ws_size,
                              hipStream_t stream) {
  const int*   pst_idx     = (const int*)  d_in[0];
  const float* color_sign  = (const float*)d_in[1];
  const float* sob_sign    = (const float*)d_in[2];
  const float* wtm         = (const float*)d_in[3];
  const float* emb_fs      = (const float*)d_in[4];
  const float* emb_va      = (const float*)d_in[5];
  const float* emb_ha      = (const float*)d_in[6];
  const float* emb_ra      = (const float*)d_in[7];
  const float* tempo_w     = (const float*)d_in[8];
  const float* fs_b        = (const float*)d_in[10];
  const float* fs_w        = (const float*)d_in[9];
  const float* absva_w     = (const float*)d_in[11];
  const float* absha_w     = (const float*)d_in[12];
  const float* absra_w     = (const float*)d_in[13];
  const float* va_w        = (const float*)d_in[14];
  const float* fsxva_w     = (const float*)d_in[15];
  const float* haxra_w     = (const float*)d_in[16];
  const float* out_va_w    = (const float*)d_in[17];
  const float* out_fsxva_w = (const float*)d_in[18];
  float* out = (float*)d_out;
  f16* ws = (f16*)d_ws;

  prepack<<<24 + 88, 256, 0, stream>>>(emb_fs, emb_va, emb_ha, emb_ra,
                                       fs_w, absva_w, absha_w, absra_w,
                                       va_w, fsxva_w, haxra_w, ws);
  rengar_main<<<NBLK, TPB, 0, stream>>>(pst_idx, color_sign, sob_sign, wtm,
                                        tempo_w, fs_b, out_va_w, out_fsxva_w,
                                        ws, out);
}

// Round 3
// 1298.523 us; speedup vs baseline: 1.3174x; 1.3174x over previous
//
#include <hip/hip_runtime.h>
#include <hip/hip_fp16.h>
#include <stdint.h>

typedef _Float16 f16;
typedef _Float16 f16x8 __attribute__((ext_vector_type(8)));
typedef float f32x4 __attribute__((ext_vector_type(4)));

#define NROWS 262144
#define MROWS 16            // rows per group
#define TPB   512           // 8 waves
#define GPB   8             // row-groups per block (table reused across these)
#define NBLK  (NROWS / (MROWS * GPB))   // 2048
#define K     192           // padded vocab
#define THR   0.9921875f

// workspace byte offsets (all f16)
#define WS_TABT 0                        // [768][192]
#define WS_W2FS (768 * 192 * 2)          // [16][768]
#define WS_W2VA (WS_W2FS + 16 * 768 * 2) // [16][640]

// LDS layout:
//  cntfx  int  [4][16][192]   @0      (49152)   -- scatter grid (phase A)
//  fsfeat f16  [16][776]      @0      (24832)   -- feature space (phase C, reuses grid)
//  vafeat f16  [16][648]      @24832  (20736, ends 45568)
//  cnt16  f16  [4][16][200]   @49152  (25600, ends 74752)  -- packed counts (phase B)
//  facc/vacc f32 [256]+[256]  @74752  (2048, ends 76800)
// total 76800 B -> 2 blocks/CU (2*76800 = 153600 <= 163840)
#define FS_STRIDE 776
#define VA_STRIDE 648
#define VA_BASE   24832
#define CNT_BASE  49152
#define ACC_BASE  74752
#define SMEM_SZ   76800

__device__ __forceinline__ f16x8 bc8(uint4 u) {
  union { uint4 u; f16x8 h; } x; x.u = u; return x.h;
}
__device__ __forceinline__ float clampv(float x) {
  return fminf(fmaxf(x, -THR), THR);
}
__device__ __forceinline__ uint32_t packh2(float a, float b) {
  union { __half2 h; uint32_t u; } cv; cv.h = __floats2half2_rn(a, b); return cv.u;
}

// ---------------- prepack ----------------------------------------------------
__global__ void prepack(const float* __restrict__ emb_fs, const float* __restrict__ emb_va,
                        const float* __restrict__ emb_ha, const float* __restrict__ emb_ra,
                        const float* __restrict__ fs_w,   const float* __restrict__ absva_w,
                        const float* __restrict__ absha_w,const float* __restrict__ absra_w,
                        const float* __restrict__ va_w,   const float* __restrict__ fsxva_w,
                        const float* __restrict__ haxra_w, f16* __restrict__ ws) {
  if (blockIdx.x < 24) {
    __shared__ float tile[192 * 33];
    int u0 = blockIdx.x * 32;
    int t = threadIdx.x;
    #pragma unroll 4
    for (int i = 0; i < 24; ++i) {
      int idx = t + 256 * i;            // 6144 = 192k x 32u
      int k = idx >> 5;
      int c = idx & 31;
      int u = u0 + c;
      float v = 0.f;
      if (k < 185) {
        if      (u < 256) v = emb_fs[k * 256 + u];
        else if (u < 512) v = emb_va[k * 256 + (u - 256)];
        else if (u < 640) v = emb_ha[k * 128 + (u - 512)];
        else              v = emb_ra[k * 128 + (u - 640)];
      }
      tile[k * 33 + c] = v;
    }
    __syncthreads();
    #pragma unroll 4
    for (int i = 0; i < 24; ++i) {
      int idx = t + 256 * i;
      int u = idx / 192;
      int k = idx % 192;
      ws[(u0 + u) * 192 + k] = (f16)tile[k * 33 + u];
    }
  } else {
    int gid = (blockIdx.x - 24) * 256 + threadIdx.x;
    if (gid < 16 * 768) {                        // w2fs[j][k]
      int j = gid / 768, k = gid % 768;
      float v = (k < 256) ? fs_w[j * 256 + k]
              : (k < 512) ? absva_w[j * 256 + (k - 256)]
              : (k < 640) ? absha_w[j * 128 + (k - 512)]
                          : absra_w[j * 128 + (k - 640)];
      ((f16*)((char*)ws + WS_W2FS))[j * 768 + k] = (f16)v;
    } else if (gid < 16 * 768 + 16 * 640) {      // w2va[j][k]
      int g = gid - 16 * 768;
      int j = g / 640, k = g % 640;
      float v = (k < 256) ? va_w[j * 256 + k]
              : (k < 512) ? fsxva_w[j * 256 + (k - 256)]
                          : haxra_w[j * 128 + (k - 512)];
      ((f16*)((char*)ws + WS_W2VA))[j * 640 + k] = (f16)v;
    }
  }
}

// issue 6 x global uint4 loads for layer-1 A tile I into BUF (register dbuf)
#define PLOADA(BUF, I) do {                         \
    const f16* p_ = apL + (I) * (16 * K);           \
    BUF[0] = *(const uint4*)(p_ +   0);             \
    BUF[1] = *(const uint4*)(p_ +  32);             \
    BUF[2] = *(const uint4*)(p_ +  64);             \
    BUF[3] = *(const uint4*)(p_ +  96);             \
    BUF[4] = *(const uint4*)(p_ + 128);             \
    BUF[5] = *(const uint4*)(p_ + 160);             \
  } while (0)

// layer-1 MFMA for tile I + fused feature store (P5); prefetch tile I+2's A
#define TILE_BODY(BUF, I) do {                                                  \
    const int t_  = w * 6 + (I);                                                \
    const int u0_ = t_ << 4;                                                    \
    const int tb_ = (u0_ < 256) ? 0 : (u0_ < 512) ? 1 : (u0_ < 640) ? 2 : 3;    \
    if (tb_ != tb_cur) {                                                        \
      tb_cur = tb_;                                                             \
      const uint32_t* bp_ = cnt16 + tb_ * 1600 + l15 * 100 + q * 4;             \
      bfr[0] = *(const uint4*)(bp_ +  0);                                       \
      bfr[1] = *(const uint4*)(bp_ + 16);                                       \
      bfr[2] = *(const uint4*)(bp_ + 32);                                       \
      bfr[3] = *(const uint4*)(bp_ + 48);                                       \
      bfr[4] = *(const uint4*)(bp_ + 64);                                       \
      bfr[5] = *(const uint4*)(bp_ + 80);                                       \
    }                                                                           \
    f32x4 a_ = {0.f, 0.f, 0.f, 0.f};                                            \
    a_ = __builtin_amdgcn_mfma_f32_16x16x32_f16(bc8(BUF[0]), bc8(bfr[0]), a_, 0, 0, 0); \
    a_ = __builtin_amdgcn_mfma_f32_16x16x32_f16(bc8(BUF[1]), bc8(bfr[1]), a_, 0, 0, 0); \
    a_ = __builtin_amdgcn_mfma_f32_16x16x32_f16(bc8(BUF[2]), bc8(bfr[2]), a_, 0, 0, 0); \
    a_ = __builtin_amdgcn_mfma_f32_16x16x32_f16(bc8(BUF[3]), bc8(bfr[3]), a_, 0, 0, 0); \
    a_ = __builtin_amdgcn_mfma_f32_16x16x32_f16(bc8(BUF[4]), bc8(bfr[4]), a_, 0, 0, 0); \
    a_ = __builtin_amdgcn_mfma_f32_16x16x32_f16(bc8(BUF[5]), bc8(bfr[5]), a_, 0, 0, 0); \
    if ((I) + 2 < 6) { PLOADA(BUF, (I) + 2); }                                  \
    const int m0_ = u0_ + q * 4;                                                \
    if (tb_ == 0) {                                                             \
      __half2* d_ = (__half2*)(smem + l15 * (FS_STRIDE * 2) + m0_ * 2);         \
      d_[0] = __floats2half2_rn(clampv(a_[0]), clampv(a_[1]));                  \
      d_[1] = __floats2half2_rn(clampv(a_[2]), clampv(a_[3]));                  \
    } else if (tb_ == 1) {                                                      \
      const int s0_ = m0_ - 256;                                                \
      float4 tw_ = *(const float4*)(tempo_w + s0_);                             \
      float b0_ = clampv(a_[0] + wtr * tw_.x);                                  \
      float b1_ = clampv(a_[1] + wtr * tw_.y);                                  \
      float b2_ = clampv(a_[2] + wtr * tw_.z);                                  \
      float b3_ = clampv(a_[3] + wtr * tw_.w);                                  \
      __half2* dv_ = (__half2*)(smem + VA_BASE + l15 * (VA_STRIDE * 2) + s0_ * 2); \
      dv_[0] = __floats2half2_rn(b0_, b1_);                                     \
      dv_[1] = __floats2half2_rn(b2_, b3_);                                     \
      __half2* df_ = (__half2*)(smem + l15 * (FS_STRIDE * 2) + (256 + s0_) * 2);\
      df_[0] = __floats2half2_rn(fabsf(b0_), fabsf(b1_));                       \
      df_[1] = __floats2half2_rn(fabsf(b2_), fabsf(b3_));                       \
    } else if (tb_ == 2) {                                                      \
      const int s0_ = m0_ - 512;                                                \
      __half2* d_ = (__half2*)(smem + l15 * (FS_STRIDE * 2) + (512 + s0_) * 2); \
      d_[0] = __floats2half2_rn(clampv(a_[0]), clampv(a_[1]));                  \
      d_[1] = __floats2half2_rn(clampv(a_[2]), clampv(a_[3]));                  \
    } else {                                                                    \
      const int s0_ = m0_ - 640;                                                \
      __half2* d_ = (__half2*)(smem + l15 * (FS_STRIDE * 2) + (640 + s0_) * 2); \
      d_[0] = __floats2half2_rn(clampv(a_[0]), clampv(a_[1]));                  \
      d_[1] = __floats2half2_rn(clampv(a_[2]), clampv(a_[3]));                  \
    }                                                                           \
  } while (0)

// ---------------- main fused kernel ------------------------------------------
__global__ __launch_bounds__(TPB, 4)   // 4 waves/EU -> 2 blocks/CU, reg cap 128
void rengar_main(const int* __restrict__ pst_idx, const float* __restrict__ color_sign,
                 const float* __restrict__ sob_sign, const float* __restrict__ wtm,
                 const float* __restrict__ tempo_w, const float* __restrict__ fs_b,
                 const float* __restrict__ out_va_w, const float* __restrict__ out_fsxva_w,
                 const f16* __restrict__ ws, float* __restrict__ out) {
  __shared__ __align__(16) char smem[SMEM_SZ];

  const int tid  = threadIdx.x;
  const int lane = tid & 63;
  const int w    = tid >> 6;          // wave 0..7
  const int l15  = lane & 15;
  const int q    = lane >> 4;

  const f16* tabT = (const f16*)((const char*)ws + WS_TABT);
  uint32_t* cnt16 = (uint32_t*)(smem + CNT_BASE);
  float* facc = (float*)(smem + ACC_BASE);
  float* vacc = facc + 256;

  // loop-invariant stream pointers (A is re-read from L2 each group; the 294 KB
  // table is resident in every XCD L2, so this is L2 traffic, not HBM)
  const f16* apL = tabT + (w * 96 + l15) * K + q * 8;
  const f16* a2p = (w < 4)
      ? ((const f16*)((const char*)ws + WS_W2FS) + l15 * 768 + w * 192 + q * 8)
      : ((const f16*)((const char*)ws + WS_W2VA) + l15 * 640 + (w - 4) * 160 + q * 8);

  float bj = 0.f, w1j = 0.f, w2j = 0.f;
  if (tid < 256) {
    int j = tid & 15;
    bj  = fs_b[j];
    w1j = out_va_w[j];
    w2j = out_fsxva_w[j];
  }

  // ---- prefetch group-0 inputs ----
  const int ebase = blockIdx.x * GPB * 512;
  int   vidx = pst_idx[ebase + tid];
  float cc   = color_sign[ebase + tid];
  float ss   = sob_sign[ebase + tid];
  float wtr  = wtm[blockIdx.x * GPB * MROWS + l15];

  // ---- prologue: zero count grid + accumulators ----
  {
    int4 z = make_int4(0, 0, 0, 0);
    int4* p = (int4*)smem;
    #pragma unroll
    for (int i = 0; i < 6; ++i) p[tid + 512 * i] = z;           // grid 0..49152
    if (tid < 128) ((int4*)(smem + ACC_BASE))[tid] = z;         // facc/vacc
  }
  __syncthreads();

  #pragma unroll 1
  for (int g = 0; g < GPB; ++g) {
    const int r0 = (blockIdx.x * GPB + g) * MROWS;
    uint4 As0[6], As1[6], bfr[6];

    // issue first two A tiles now; latency hidden under scatter + convert
    PLOADA(As0, 0);
    PLOADA(As1, 1);

    // ---- P2: scatter (LDS int atomics, scale 2^16) -- grid pre-zeroed
    {
      int* base = (int*)smem + (tid >> 5) * K + vidx;
      atomicAdd(base + 0 * MROWS * K, 65536);
      atomicAdd(base + 1 * MROWS * K, __float2int_rn(cc * 65536.f));
      atomicAdd(base + 2 * MROWS * K, __float2int_rn(ss * 65536.f));
      atomicAdd(base + 3 * MROWS * K, __float2int_rn(cc * ss * 65536.f));
    }
    // prefetch next group's inputs
    float nwt = wtr;
    if (g + 1 < GPB) {
      int nb = ebase + (g + 1) * 512;
      vidx = pst_idx[nb + tid];
      cc   = color_sign[nb + tid];
      ss   = sob_sign[nb + tid];
      nwt  = wtm[r0 + MROWS + l15];
    }
    __syncthreads();                                       // (1)

    // ---- P3: one-pass convert int grid -> cnt16 (disjoint region, no WAR)
    {
      const float inv = 1.f / 65536.f;
      const int4* src = (const int4*)smem;
      #pragma unroll
      for (int i = 0; i < 6; ++i) {
        int idx = tid + 512 * i;            // int4 index; 4 ints of one row
        int4 t4 = src[idx];                 // lane-consecutive: conflict-free
        int tb  = idx / 768;
        int rem = idx - tb * 768;
        int row = rem / 48;
        int k2  = (rem - row * 48) * 2;     // (k0>>1), even
        uint2 o;
        o.x = packh2((float)t4.x * inv, (float)t4.y * inv);
        o.y = packh2((float)t4.z * inv, (float)t4.w * inv);
        *(uint2*)(cnt16 + tb * 1600 + row * 100 + k2) = o;  // lane-consecutive
      }
    }
    __syncthreads();                                       // (2)

    // ---- P4+P5 fused: layer-1 GEMM (A streamed from L2, depth-2 pipeline),
    //      clamp + feature store per tile immediately after its MFMA chain.
    //      Feature region (0..45568) is disjoint from cnt16 (49152..) => no barrier.
    {
      int tb_cur = -1;
      TILE_BODY(As0, 0);
      TILE_BODY(As1, 1);
      TILE_BODY(As0, 2);
      TILE_BODY(As1, 3);
      TILE_BODY(As0, 4);
      TILE_BODY(As1, 5);
    }
    __syncthreads();                                       // (3)

    // ---- stream layer-2 A fragments (live only through P6/P7)
    uint4 a2s[6];
    if (w < 4) {
      #pragma unroll
      for (int ks = 0; ks < 6; ++ks) a2s[ks] = *(const uint4*)(a2p + ks * 32);
    } else {
      #pragma unroll
      for (int ks = 0; ks < 5; ++ks) a2s[ks] = *(const uint4*)(a2p + ks * 32);
    }

    // ---- P6: derived features: ab, |h|, |r|, h*r
    {
      uint32_t* fs32 = (uint32_t*)smem;
      uint32_t* va32 = (uint32_t*)(smem + VA_BASE);
      #pragma unroll
      for (int it = 0; it < 6; ++it) {
        int p = tid + 512 * it;
        if (p < 2048) {
          int row = p >> 7, kp = p & 127;
          union { uint32_t u; __half2 h; } a, b, r;
          a.u = fs32[row * 388 + kp];
          b.u = va32[row * 324 + kp];
          r.h = __hmul2(a.h, b.h);
          va32[row * 324 + 128 + kp] = r.u;
        } else {
          int pc = p - 2048;
          int row = pc >> 6, kp = pc & 63;
          union { uint32_t u; __half2 h; } h2, r2, pr;
          h2.u = fs32[row * 388 + 256 + kp];
          r2.u = fs32[row * 388 + 320 + kp];
          pr.h = __hmul2(h2.h, r2.h);
          fs32[row * 388 + 256 + kp] = h2.u & 0x7FFF7FFFu;
          fs32[row * 388 + 320 + kp] = r2.u & 0x7FFF7FFFu;
          va32[row * 324 + 256 + kp] = pr.u;
        }
      }
    }
    __syncthreads();                                       // (4)

    // ---- P7: layer-2 split-K across all 8 waves, combine via LDS f32 atomics
    {
      f32x4 a2acc = {0.f, 0.f, 0.f, 0.f};
      if (w < 4) {
        #pragma unroll
        for (int ks = 0; ks < 6; ++ks) {
          int k = w * 192 + ks * 32 + q * 8;
          uint4 bf = *(const uint4*)(smem + l15 * (FS_STRIDE * 2) + k * 2);
          a2acc = __builtin_amdgcn_mfma_f32_16x16x32_f16(bc8(a2s[ks]), bc8(bf), a2acc, 0, 0, 0);
        }
      } else {
        #pragma unroll
        for (int ks = 0; ks < 5; ++ks) {
          int k = (w - 4) * 160 + ks * 32 + q * 8;
          uint4 bf = *(const uint4*)(smem + VA_BASE + l15 * (VA_STRIDE * 2) + k * 2);
          a2acc = __builtin_amdgcn_mfma_f32_16x16x32_f16(bc8(a2s[ks]), bc8(bf), a2acc, 0, 0, 0);
        }
      }
      float* dstacc = (w < 4) ? facc : vacc;
      int base = l15 << 4;               // l15 = batch row (D col)
      #pragma unroll
      for (int r = 0; r < 4; ++r) {
        int j = q * 4 + r;               // output index
        atomicAdd(&dstacc[base + ((j + l15) & 15)], a2acc[r]);  // staggered banks
      }
    }
    __syncthreads();                                       // (5)

    // ---- P8: waves 0-3: read accum (+re-zero), bias/clamp, shfl reduce, out.
    //          waves 4-7: re-zero the 48 KiB count grid for the next group.
    if (tid < 256) {
      int b = tid >> 4, j = tid & 15;
      int idx = (b << 4) | ((j + b) & 15);
      float f = facc[idx];
      float v = vacc[idx];
      facc[idx] = 0.f;
      vacc[idx] = 0.f;
      f = clampv(f + bj);
      v = clampv(v);
      float rr = v * w1j + f * v * w2j;
      rr += __shfl_xor(rr, 1);
      rr += __shfl_xor(rr, 2);
      rr += __shfl_xor(rr, 4);
      rr += __shfl_xor(rr, 8);
      if (j == 0) out[r0 + b] = rr;
    } else if (g + 1 < GPB) {
      int4 z = make_int4(0, 0, 0, 0);
      int4* p = (int4*)smem;
      int t2 = tid - 256;
      #pragma unroll
      for (int i = 0; i < 12; ++i) p[t2 + 256 * i] = z;    // grid 0..49152
    }
    __syncthreads();                                       // (6)
    wtr = nwt;
  }
}

extern "C" void kernel_launch(void* const* d_in, const int* in_sizes, int n_in,
                              void* d_out, int out_size, void* d_ws, size_t ws_size,
                              hipStream_t stream) {
  const int*   pst_idx     = (const int*)  d_in[0];
  const float* color_sign  = (const float*)d_in[1];
  const float* sob_sign    = (const float*)d_in[2];
  const float* wtm         = (const float*)d_in[3];
  const float* emb_fs      = (const float*)d_in[4];
  const float* emb_va      = (const float*)d_in[5];
  const float* emb_ha      = (const float*)d_in[6];
  const float* emb_ra      = (const float*)d_in[7];
  const float* tempo_w     = (const float*)d_in[8];
  const float* fs_b        = (const float*)d_in[10];
  const float* fs_w        = (const float*)d_in[9];
  const float* absva_w     = (const float*)d_in[11];
  const float* absha_w     = (const float*)d_in[12];
  const float* absra_w     = (const float*)d_in[13];
  const float* va_w        = (const float*)d_in[14];
  const float* fsxva_w     = (const float*)d_in[15];
  const float* haxra_w     = (const float*)d_in[16];
  const float* out_va_w    = (const float*)d_in[17];
  const float* out_fsxva_w = (const float*)d_in[18];
  float* out = (float*)d_out;
  f16* ws = (f16*)d_ws;

  prepack<<<24 + 88, 256, 0, stream>>>(emb_fs, emb_va, emb_ha, emb_ra,
                                       fs_w, absva_w, absha_w, absra_w,
                                       va_w, fsxva_w, haxra_w, ws);
  rengar_main<<<NBLK, TPB, 0, stream>>>(pst_idx, color_sign, sob_sign, wtm,
                                        tempo_w, fs_b, out_va_w, out_fsxva_w,
                                        ws, out);
}

// Round 4
// 568.378 us; speedup vs baseline: 3.0098x; 2.2846x over previous
//
#include <hip/hip_runtime.h>
#include <hip/hip_fp16.h>
#include <stdint.h>

typedef _Float16 f16;
typedef _Float16 f16x8 __attribute__((ext_vector_type(8)));
typedef float f32x4 __attribute__((ext_vector_type(4)));

#define NROWS 262144
#define MROWS 16            // rows per group
#define TPB   512           // 8 waves
#define GPB   8             // row-groups per block (table reused across these)
#define NBLK  (NROWS / (MROWS * GPB))   // 2048
#define K     192           // padded vocab
#define THR   0.9921875f

// workspace byte offsets (all f16)
#define WS_TABT 0                        // [768][192]
#define WS_W2FS (768 * 192 * 2)          // [16][768]
#define WS_W2VA (WS_W2FS + 16 * 768 * 2) // [16][640]

// LDS layout (1 block/CU -> plenty of room):
//  cntfx  int  [4][16][192]   @0      (49152)   -- scatter grid (phase A)
//  fsfeat f16  [16][776]      @0      (24832)   -- feature space (phase C, reuses grid)
//  vafeat f16  [16][648]      @24832  (20736, ends 45568)
//  cnt16  f16  [4][16][200]   @49152  (25600, ends 74752)  -- packed counts (phase B)
//  facc/vacc f32 [256]+[256]  @74752  (2048, ends 76800)
#define FS_STRIDE 776
#define VA_STRIDE 648
#define VA_BASE   24832
#define CNT_BASE  49152
#define ACC_BASE  74752
#define SMEM_SZ   76800

__device__ __forceinline__ f16x8 bc8(uint4 u) {
  union { uint4 u; f16x8 h; } x; x.u = u; return x.h;
}
__device__ __forceinline__ float clampv(float x) {
  return fminf(fmaxf(x, -THR), THR);
}
__device__ __forceinline__ uint32_t packh2(float a, float b) {
  union { __half2 h; uint32_t u; } cv; cv.h = __floats2half2_rn(a, b); return cv.u;
}
__device__ __forceinline__ f32x4 chain6(const uint4* af, const uint4* bf) {
  f32x4 a = {0.f, 0.f, 0.f, 0.f};
  #pragma unroll
  for (int ks = 0; ks < 6; ++ks)
    a = __builtin_amdgcn_mfma_f32_16x16x32_f16(bc8(af[ks]), bc8(bf[ks]), a, 0, 0, 0);
  return a;
}

// ---------------- prepack ----------------------------------------------------
__global__ void prepack(const float* __restrict__ emb_fs, const float* __restrict__ emb_va,
                        const float* __restrict__ emb_ha, const float* __restrict__ emb_ra,
                        const float* __restrict__ fs_w,   const float* __restrict__ absva_w,
                        const float* __restrict__ absha_w,const float* __restrict__ absra_w,
                        const float* __restrict__ va_w,   const float* __restrict__ fsxva_w,
                        const float* __restrict__ haxra_w, f16* __restrict__ ws) {
  if (blockIdx.x < 24) {
    __shared__ float tile[192 * 33];
    int u0 = blockIdx.x * 32;
    int t = threadIdx.x;
    #pragma unroll 4
    for (int i = 0; i < 24; ++i) {
      int idx = t + 256 * i;            // 6144 = 192k x 32u
      int k = idx >> 5;
      int c = idx & 31;
      int u = u0 + c;
      float v = 0.f;
      if (k < 185) {
        if      (u < 256) v = emb_fs[k * 256 + u];
        else if (u < 512) v = emb_va[k * 256 + (u - 256)];
        else if (u < 640) v = emb_ha[k * 128 + (u - 512)];
        else              v = emb_ra[k * 128 + (u - 640)];
      }
      tile[k * 33 + c] = v;
    }
    __syncthreads();
    #pragma unroll 4
    for (int i = 0; i < 24; ++i) {
      int idx = t + 256 * i;
      int u = idx / 192;
      int k = idx % 192;
      ws[(u0 + u) * 192 + k] = (f16)tile[k * 33 + u];
    }
  } else {
    int gid = (blockIdx.x - 24) * 256 + threadIdx.x;
    if (gid < 16 * 768) {                        // w2fs[j][k]
      int j = gid / 768, k = gid % 768;
      float v = (k < 256) ? fs_w[j * 256 + k]
              : (k < 512) ? absva_w[j * 256 + (k - 256)]
              : (k < 640) ? absha_w[j * 128 + (k - 512)]
                          : absra_w[j * 128 + (k - 640)];
      ((f16*)((char*)ws + WS_W2FS))[j * 768 + k] = (f16)v;
    } else if (gid < 16 * 768 + 16 * 640) {      // w2va[j][k]
      int g = gid - 16 * 768;
      int j = g / 640, k = g % 640;
      float v = (k < 256) ? va_w[j * 256 + k]
              : (k < 512) ? fsxva_w[j * 256 + (k - 256)]
                          : haxra_w[j * 128 + (k - 512)];
      ((f16*)((char*)ws + WS_W2VA))[j * 640 + k] = (f16)v;
    }
  }
}

// ---------------- main fused kernel ------------------------------------------
// 2 waves/EU (8 waves/CU, 1 block/CU): full register budget for resident A.
__global__ __launch_bounds__(TPB, 2)
void rengar_main(const int* __restrict__ pst_idx, const float* __restrict__ color_sign,
                 const float* __restrict__ sob_sign, const float* __restrict__ wtm,
                 const float* __restrict__ tempo_w, const float* __restrict__ fs_b,
                 const float* __restrict__ out_va_w, const float* __restrict__ out_fsxva_w,
                 const f16* __restrict__ ws, float* __restrict__ out) {
  __shared__ __align__(16) char smem[SMEM_SZ];

  const int tid  = threadIdx.x;
  const int lane = tid & 63;
  const int w    = tid >> 6;          // wave 0..7
  const int l15  = lane & 15;
  const int q    = lane >> 4;

  const f16* tabT = (const f16*)((const char*)ws + WS_TABT);
  uint32_t* cnt16 = (uint32_t*)(smem + CNT_BASE);
  float* facc = (float*)(smem + ACC_BASE);
  float* vacc = facc + 256;

  // ---- hoist layer-1 A fragments: wave-local pairing!
  //      tile order: fs(32w), fs(32w+16), va(32w), va(32w+16), ha(16w), ra(16w)
  //      -> all derived features (|va|, fs*va, |h|, |r|, h*r) are wave-local.
  uint4 afr1[36];
  {
    const int bases[6] = { 32 * w, 32 * w + 16, 256 + 32 * w, 272 + 32 * w,
                           512 + 16 * w, 640 + 16 * w };
    #pragma unroll
    for (int i = 0; i < 6; ++i) {
      const f16* ap = tabT + (bases[i] + l15) * K + q * 8;
      #pragma unroll
      for (int ks = 0; ks < 6; ++ks) afr1[i * 6 + ks] = *(const uint4*)(ap + ks * 32);
    }
  }

  // ---- hoist layer-2 A fragments (split-K: fs -> waves 0-3, va -> waves 4-7)
  uint4 a2[6];
  if (w < 4) {
    const f16* A = (const f16*)((const char*)ws + WS_W2FS) + l15 * 768 + w * 192 + q * 8;
    #pragma unroll
    for (int ks = 0; ks < 6; ++ks) a2[ks] = *(const uint4*)(A + ks * 32);
  } else {
    const f16* A = (const f16*)((const char*)ws + WS_W2VA) + l15 * 640 + (w - 4) * 160 + q * 8;
    #pragma unroll
    for (int ks = 0; ks < 5; ++ks) a2[ks] = *(const uint4*)(A + ks * 32);
  }

  float bj = 0.f, w1j = 0.f, w2j = 0.f;
  if (tid < 256) {
    int j = tid & 15;
    bj  = fs_b[j];
    w1j = out_va_w[j];
    w2j = out_fsxva_w[j];
  }

  // ---- prefetch group-0 inputs ----
  const int ebase = blockIdx.x * GPB * 512;
  int   vidx = pst_idx[ebase + tid];
  float cc   = color_sign[ebase + tid];
  float ss   = sob_sign[ebase + tid];
  float wtr  = wtm[blockIdx.x * GPB * MROWS + l15];

  // ---- prologue: zero count grid + accumulators ----
  {
    int4 z = make_int4(0, 0, 0, 0);
    int4* p = (int4*)smem;
    #pragma unroll
    for (int i = 0; i < 6; ++i) p[tid + 512 * i] = z;           // grid 0..49152
    if (tid < 128) ((int4*)(smem + ACC_BASE))[tid] = z;         // facc/vacc
  }
  __syncthreads();

  #pragma unroll 1
  for (int g = 0; g < GPB; ++g) {
    const int r0 = (blockIdx.x * GPB + g) * MROWS;

    // ---- P2: scatter (LDS int atomics, scale 2^16) -- grid pre-zeroed
    {
      int* base = (int*)smem + (tid >> 5) * K + vidx;
      atomicAdd(base + 0 * MROWS * K, 65536);
      atomicAdd(base + 1 * MROWS * K, __float2int_rn(cc * 65536.f));
      atomicAdd(base + 2 * MROWS * K, __float2int_rn(ss * 65536.f));
      atomicAdd(base + 3 * MROWS * K, __float2int_rn(cc * ss * 65536.f));
    }
    // prefetch next group's inputs
    float nwt = wtr;
    if (g + 1 < GPB) {
      int nb = ebase + (g + 1) * 512;
      vidx = pst_idx[nb + tid];
      cc   = color_sign[nb + tid];
      ss   = sob_sign[nb + tid];
      nwt  = wtm[r0 + MROWS + l15];
    }
    __syncthreads();                                       // (1)

    // ---- P3: one-pass convert int grid -> cnt16 (disjoint region, no WAR)
    {
      const float inv = 1.f / 65536.f;
      const int4* src = (const int4*)smem;
      #pragma unroll
      for (int i = 0; i < 6; ++i) {
        int idx = tid + 512 * i;            // int4 index; 4 ints of one row
        int4 t4 = src[idx];                 // lane-consecutive: conflict-free
        int tb  = idx / 768;
        int rem = idx - tb * 768;
        int row = rem / 48;
        int k2  = (rem - row * 48) * 2;     // (k0>>1), even
        uint2 o;
        o.x = packh2((float)t4.x * inv, (float)t4.y * inv);
        o.y = packh2((float)t4.z * inv, (float)t4.w * inv);
        *(uint2*)(cnt16 + tb * 1600 + row * 100 + k2) = o;  // lane-consecutive
      }
    }
    __syncthreads();                                       // (2)

    // ---- P4+P5+P6 fused: layer-1 GEMM + clamp + ALL derived features in
    //      registers (wave-local pairing), single store pass.
    //      Feature region (0..45568) disjoint from cnt16 (49152..): no barrier.
    {
      uint4 bfrA[6], bfrB[6];
      const uint32_t* bpA = cnt16 + 0 * 1600 + l15 * 100 + q * 4;  // fs counts
      const uint32_t* bpB = cnt16 + 1 * 1600 + l15 * 100 + q * 4;  // va counts
      #pragma unroll
      for (int ks = 0; ks < 6; ++ks) {
        bfrA[ks] = *(const uint4*)(bpA + ks * 16);
        bfrB[ks] = *(const uint4*)(bpB + ks * 16);
      }
      #pragma unroll
      for (int half = 0; half < 2; ++half) {
        f32x4 fA = chain6(&afr1[(0 + half) * 6], bfrA);   // fs1 tile
        f32x4 vA = chain6(&afr1[(2 + half) * 6], bfrB);   // va1 tile (same u range)
        const int m0 = 32 * w + 16 * half + q * 4;
        float4 tw = *(const float4*)(tempo_w + m0);
        float a0 = clampv(fA[0]), a1 = clampv(fA[1]);
        float a2c = clampv(fA[2]), a3 = clampv(fA[3]);
        float b0 = clampv(vA[0] + wtr * tw.x);
        float b1 = clampv(vA[1] + wtr * tw.y);
        float b2 = clampv(vA[2] + wtr * tw.z);
        float b3 = clampv(vA[3] + wtr * tw.w);
        char* fsrow = smem + l15 * (FS_STRIDE * 2);
        char* varow = smem + VA_BASE + l15 * (VA_STRIDE * 2);
        // fs1
        ((uint32_t*)(fsrow + m0 * 2))[0] = packh2(a0, a1);
        ((uint32_t*)(fsrow + m0 * 2))[1] = packh2(a2c, a3);
        // |va1|
        ((uint32_t*)(fsrow + (256 + m0) * 2))[0] = packh2(fabsf(b0), fabsf(b1));
        ((uint32_t*)(fsrow + (256 + m0) * 2))[1] = packh2(fabsf(b2), fabsf(b3));
        // va1
        ((uint32_t*)(varow + m0 * 2))[0] = packh2(b0, b1);
        ((uint32_t*)(varow + m0 * 2))[1] = packh2(b2, b3);
        // fs1*va1
        ((uint32_t*)(varow + (256 + m0) * 2))[0] = packh2(a0 * b0, a1 * b1);
        ((uint32_t*)(varow + (256 + m0) * 2))[1] = packh2(a2c * b2, a3 * b3);
      }
      {
        const uint32_t* bpH = cnt16 + 2 * 1600 + l15 * 100 + q * 4;  // sob counts
        const uint32_t* bpR = cnt16 + 3 * 1600 + l15 * 100 + q * 4;  // c*s counts
        #pragma unroll
        for (int ks = 0; ks < 6; ++ks) {
          bfrA[ks] = *(const uint4*)(bpH + ks * 16);
          bfrB[ks] = *(const uint4*)(bpR + ks * 16);
        }
        f32x4 hA = chain6(&afr1[4 * 6], bfrA);            // ha1 tile
        f32x4 rA = chain6(&afr1[5 * 6], bfrB);            // ra1 tile (same s range)
        const int s0 = 16 * w + q * 4;
        float h0 = clampv(hA[0]), h1 = clampv(hA[1]);
        float h2 = clampv(hA[2]), h3 = clampv(hA[3]);
        float r0c = clampv(rA[0]), r1 = clampv(rA[1]);
        float r2 = clampv(rA[2]), r3 = clampv(rA[3]);
        char* fsrow = smem + l15 * (FS_STRIDE * 2);
        char* varow = smem + VA_BASE + l15 * (VA_STRIDE * 2);
        // |ha1|
        ((uint32_t*)(fsrow + (512 + s0) * 2))[0] = packh2(fabsf(h0), fabsf(h1));
        ((uint32_t*)(fsrow + (512 + s0) * 2))[1] = packh2(fabsf(h2), fabsf(h3));
        // |ra1|
        ((uint32_t*)(fsrow + (640 + s0) * 2))[0] = packh2(fabsf(r0c), fabsf(r1));
        ((uint32_t*)(fsrow + (640 + s0) * 2))[1] = packh2(fabsf(r2), fabsf(r3));
        // ha1*ra1
        ((uint32_t*)(varow + (512 + s0) * 2))[0] = packh2(h0 * r0c, h1 * r1);
        ((uint32_t*)(varow + (512 + s0) * 2))[1] = packh2(h2 * r2, h3 * r3);
      }
    }
    __syncthreads();                                       // (3)

    // ---- P7: layer-2 split-K across all 8 waves, combine via LDS f32 atomics
    {
      f32x4 a2acc = {0.f, 0.f, 0.f, 0.f};
      if (w < 4) {
        #pragma unroll
        for (int ks = 0; ks < 6; ++ks) {
          int k = w * 192 + ks * 32 + q * 8;
          uint4 bf = *(const uint4*)(smem + l15 * (FS_STRIDE * 2) + k * 2);
          a2acc = __builtin_amdgcn_mfma_f32_16x16x32_f16(bc8(a2[ks]), bc8(bf), a2acc, 0, 0, 0);
        }
      } else {
        #pragma unroll
        for (int ks = 0; ks < 5; ++ks) {
          int k = (w - 4) * 160 + ks * 32 + q * 8;
          uint4 bf = *(const uint4*)(smem + VA_BASE + l15 * (VA_STRIDE * 2) + k * 2);
          a2acc = __builtin_amdgcn_mfma_f32_16x16x32_f16(bc8(a2[ks]), bc8(bf), a2acc, 0, 0, 0);
        }
      }
      float* dstacc = (w < 4) ? facc : vacc;
      int base = l15 << 4;               // l15 = batch row (D col)
      #pragma unroll
      for (int r = 0; r < 4; ++r) {
        int j = q * 4 + r;               // output index
        atomicAdd(&dstacc[base + ((j + l15) & 15)], a2acc[r]);  // staggered banks
      }
    }
    __syncthreads();                                       // (4)

    // ---- P8: waves 0-3: read accum (+re-zero), bias/clamp, shfl reduce, out.
    //          waves 4-7: re-zero the 48 KiB count grid for the next group.
    if (tid < 256) {
      int b = tid >> 4, j = tid & 15;
      int idx = (b << 4) | ((j + b) & 15);
      float f = facc[idx];
      float v = vacc[idx];
      facc[idx] = 0.f;
      vacc[idx] = 0.f;
      f = clampv(f + bj);
      v = clampv(v);
      float rr = v * w1j + f * v * w2j;
      rr += __shfl_xor(rr, 1);
      rr += __shfl_xor(rr, 2);
      rr += __shfl_xor(rr, 4);
      rr += __shfl_xor(rr, 8);
      if (j == 0) out[r0 + b] = rr;
    } else if (g + 1 < GPB) {
      int4 z = make_int4(0, 0, 0, 0);
      int4* p = (int4*)smem;
      int t2 = tid - 256;
      #pragma unroll
      for (int i = 0; i < 12; ++i) p[t2 + 256 * i] = z;    // grid 0..49152
    }
    __syncthreads();                                       // (5)
    wtr = nwt;
  }
}

extern "C" void kernel_launch(void* const* d_in, const int* in_sizes, int n_in,
                              void* d_out, int out_size, void* d_ws, size_t ws_size,
                              hipStream_t stream) {
  const int*   pst_idx     = (const int*)  d_in[0];
  const float* color_sign  = (const float*)d_in[1];
  const float* sob_sign    = (const float*)d_in[2];
  const float* wtm         = (const float*)d_in[3];
  const float* emb_fs      = (const float*)d_in[4];
  const float* emb_va      = (const float*)d_in[5];
  const float* emb_ha      = (const float*)d_in[6];
  const float* emb_ra      = (const float*)d_in[7];
  const float* tempo_w     = (const float*)d_in[8];
  const float* fs_b        = (const float*)d_in[10];
  const float* fs_w        = (const float*)d_in[9];
  const float* absva_w     = (const float*)d_in[11];
  const float* absha_w     = (const float*)d_in[12];
  const float* absra_w     = (const float*)d_in[13];
  const float* va_w        = (const float*)d_in[14];
  const float* fsxva_w     = (const float*)d_in[15];
  const float* haxra_w     = (const float*)d_in[16];
  const float* out_va_w    = (const float*)d_in[17];
  const float* out_fsxva_w = (const float*)d_in[18];
  float* out = (float*)d_out;
  f16* ws = (f16*)d_ws;

  prepack<<<24 + 88, 256, 0, stream>>>(emb_fs, emb_va, emb_ha, emb_ra,
                                       fs_w, absva_w, absha_w, absra_w,
                                       va_w, fsxva_w, haxra_w, ws);
  rengar_main<<<NBLK, TPB, 0, stream>>>(pst_idx, color_sign, sob_sign, wtm,
                                        tempo_w, fs_b, out_va_w, out_fsxva_w,
                                        ws, out);
}